// Round 3
// baseline (64.316 us; speedup 1.0000x reference)
//
#include <hip/hip_runtime.h>

#define CHUNK 8
#define NCHUNK 64
#define TDIM 512
#define HW 9216            // 96*96
#define NT 256
#define F4_PER_CH (HW/4)   // 2304 float4 per channel

#define SPLIT1 3           // reduce kernel: blocks per chunk
#define ITERS1 (F4_PER_CH/(NT*SPLIT1))  // 3
#define SPLIT2 9           // map kernel: blocks per chunk (1 float4/thread)

typedef float floatx4 __attribute__((ext_vector_type(4)));

__host__ __device__ constexpr int TRI(int c, int j) {       // c<=j incl diag, 36 entries
    return (c*(15-c))/2 + j;
}
__host__ __device__ constexpr int PairIdx(int c, int j) {   // c<j strict, 28 entries
    return 7*c - (c*(c-1))/2 + (j - c - 1);
}

// ---------------- K1: partial Gram + row sums per (chunk, split) ----------------
__global__ __launch_bounds__(NT, 4)
void k1_reduce(const float* __restrict__ x, float* __restrict__ ws)
{
    const int bid   = blockIdx.x;
    const int chunk = bid / SPLIT1;            // 0..511
    const int split = bid - chunk*SPLIT1;      // 0..2
    const int b     = chunk >> 6;
    const int n     = chunk & 63;
    const int tid   = threadIdx.x;
    const int lane  = tid & 63;
    const int wid   = tid >> 6;

    const float* xb = x + ((size_t)(b*TDIM + n*CHUNK)) * HW;

    __shared__ float red[4][44];

    float g[36], sr[8];
    #pragma unroll
    for (int i = 0; i < 36; ++i) g[i] = 0.f;
    #pragma unroll
    for (int c = 0; c < 8; ++c) sr[c] = 0.f;

    #pragma unroll
    for (int it = 0; it < ITERS1; ++it) {
        const int f = split*(NT*ITERS1) + it*NT + tid;
        floatx4 q[8];
        #pragma unroll
        for (int c = 0; c < 8; ++c)
            q[c] = reinterpret_cast<const floatx4*>(xb + (size_t)c*HW)[f];
        #pragma unroll
        for (int u = 0; u < 4; ++u) {
            float xv[8];
            #pragma unroll
            for (int c = 0; c < 8; ++c) xv[c] = q[c][u];
            #pragma unroll
            for (int c = 0; c < 8; ++c) sr[c] += xv[c];
            #pragma unroll
            for (int c = 0; c < 8; ++c) {
                #pragma unroll
                for (int j = c; j < 8; ++j)
                    g[TRI(c,j)] += xv[c]*xv[j];
            }
        }
    }

    // wave butterfly reduce
    #pragma unroll
    for (int i = 0; i < 36; ++i) {
        g[i] += __shfl_xor(g[i], 1);  g[i] += __shfl_xor(g[i], 2);
        g[i] += __shfl_xor(g[i], 4);  g[i] += __shfl_xor(g[i], 8);
        g[i] += __shfl_xor(g[i], 16); g[i] += __shfl_xor(g[i], 32);
    }
    #pragma unroll
    for (int c = 0; c < 8; ++c) {
        sr[c] += __shfl_xor(sr[c], 1);  sr[c] += __shfl_xor(sr[c], 2);
        sr[c] += __shfl_xor(sr[c], 4);  sr[c] += __shfl_xor(sr[c], 8);
        sr[c] += __shfl_xor(sr[c], 16); sr[c] += __shfl_xor(sr[c], 32);
    }
    if (lane == 0) {
        #pragma unroll
        for (int i = 0; i < 36; ++i) red[wid][i] = g[i];
        #pragma unroll
        for (int c = 0; c < 8; ++c) red[wid][36+c] = sr[c];
    }
    __syncthreads();
    if (tid < 44) {
        float v = red[0][tid] + red[1][tid] + red[2][tid] + red[3][tid];
        ws[(size_t)(chunk*SPLIT1 + split)*44 + tid] = v;
    }
}

// ---------------- K2: tiny attention (redundant per block) + map ----------------
__global__ __launch_bounds__(NT, 4)
void k2_map(const float* __restrict__ x,
            const float* __restrict__ Wq, const float* __restrict__ bq,
            const float* __restrict__ Wk, const float* __restrict__ bk,
            const float* __restrict__ Wv, const float* __restrict__ bv,
            const float* __restrict__ ws,
            float* __restrict__ out)
{
    const int bid   = blockIdx.x;
    const int chunk = bid / SPLIT2;            // 0..511
    const int split = bid - chunk*SPLIT2;      // 0..8
    const int b     = chunk >> 6;
    const int n     = chunk & 63;
    const int tid   = threadIdx.x;

    const float* xb = x + ((size_t)(b*TDIM + n*CHUNK)) * HW;
    float* ob = out + ((size_t)(b*NCHUNK + n)) * HW;

    __shared__ float Gf[64];
    __shared__ float sf[8];
    __shared__ float Mld[64];
    __shared__ float tld[8];

    // issue pixel loads immediately; they stay in flight during attention math
    const int f = split*NT + tid;
    floatx4 q[8];
    #pragma unroll
    for (int c = 0; c < 8; ++c)
        q[c] = reinterpret_cast<const floatx4*>(xb + (size_t)c*HW)[f];

    // sum the 3 partials into full Gram + row sums
    if (tid < 44) {
        const float* p = ws + (size_t)chunk*SPLIT1*44;
        float v = p[tid] + p[44 + tid] + p[88 + tid];
        if (tid < 36) {
            int c = 0, base = 0;
            for (; c < 8; ++c) { int w = 8 - c; if (tid < base + w) break; base += w; }
            int j = c + (tid - base);
            Gf[c*8+j] = v;
            Gf[j*8+c] = v;
        } else {
            sf[tid-36] = v;
        }
    }
    __syncthreads();

    // tiny 8x8 attention on wave 0
    if (tid < 64) {
        const int qi = tid >> 3;
        const int ki = tid & 7;
        float wq[8], wk[8];
        #pragma unroll
        for (int c = 0; c < 8; ++c) {
            wq[c] = Wq[n*64 + qi*8 + c];
            wk[c] = Wk[n*64 + ki*8 + c];
        }
        float sc = 0.f, qs = 0.f, ks_ = 0.f;
        #pragma unroll
        for (int c = 0; c < 8; ++c) {
            float tmp = 0.f;
            #pragma unroll
            for (int d = 0; d < 8; ++d) tmp += Gf[c*8+d]*wk[d];
            sc += wq[c]*tmp;
            qs += wq[c]*sf[c];
            ks_ += wk[c]*sf[c];
        }
        const float bqv = bq[n*8+qi];
        const float bkv = bk[n*8+ki];
        sc += qs*bkv + bqv*ks_ + (float)HW * bqv * bkv;
        sc *= (1.0f/96.0f);   // 1/sqrt(9216)

        float m = sc;
        m = fmaxf(m, __shfl_xor(m, 1, 8));
        m = fmaxf(m, __shfl_xor(m, 2, 8));
        m = fmaxf(m, __shfl_xor(m, 4, 8));
        float e = expf(sc - m);
        float se = e;
        se += __shfl_xor(se, 1, 8);
        se += __shfl_xor(se, 2, 8);
        se += __shfl_xor(se, 4, 8);
        const float attn = e / se;

        float mv = 0.f;
        #pragma unroll
        for (int k = 0; k < 8; ++k) {
            float ak = __shfl(attn, k, 8);
            mv += ak * Wv[n*64 + k*8 + ki];
        }
        Mld[qi*8 + ki] = mv;

        float tv = attn * bv[n*8 + ki];
        tv += __shfl_xor(tv, 1, 8);
        tv += __shfl_xor(tv, 2, 8);
        tv += __shfl_xor(tv, 4, 8);
        if (ki == 0) tld[qi] = tv;
    }
    __syncthreads();

    // fold coefficients (broadcast LDS reads)
    float diag[8], tt[8], su[28];
    #pragma unroll
    for (int c = 0; c < 8; ++c) { diag[c] = Mld[c*9]; tt[c] = tld[c]; }
    #pragma unroll
    for (int c = 0; c < 8; ++c) {
        #pragma unroll
        for (int j = c+1; j < 8; ++j)
            su[PairIdx(c,j)] = Mld[c*8+j] + Mld[j*8+c];
    }

    // apply quadratic form to the (already in-flight) pixel data
    floatx4 o;
    #pragma unroll
    for (int u = 0; u < 4; ++u) {
        float xv[8];
        #pragma unroll
        for (int c = 0; c < 8; ++c) xv[c] = q[c][u];
        float acc = 0.f;
        #pragma unroll
        for (int c = 0; c < 8; ++c) acc += tt[c]*xv[c];
        #pragma unroll
        for (int c = 0; c < 8; ++c) acc += diag[c]*xv[c]*xv[c];
        #pragma unroll
        for (int c = 0; c < 8; ++c) {
            #pragma unroll
            for (int j = c+1; j < 8; ++j)
                acc += su[PairIdx(c,j)]*xv[c]*xv[j];
        }
        o[u] = acc;
    }
    reinterpret_cast<floatx4*>(ob)[f] = o;
}

extern "C" void kernel_launch(void* const* d_in, const int* in_sizes, int n_in,
                              void* d_out, int out_size, void* d_ws, size_t ws_size,
                              hipStream_t stream) {
    const float* x  = (const float*)d_in[0];
    const float* Wq = (const float*)d_in[1];
    const float* bq = (const float*)d_in[2];
    const float* Wk = (const float*)d_in[3];
    const float* bk = (const float*)d_in[4];
    const float* Wv = (const float*)d_in[5];
    const float* bv = (const float*)d_in[6];
    float* out = (float*)d_out;
    float* ws  = (float*)d_ws;   // 512*3*44 floats = 270 KB

    k1_reduce<<<dim3(512*SPLIT1), dim3(NT), 0, stream>>>(x, ws);
    k2_map<<<dim3(512*SPLIT2), dim3(NT), 0, stream>>>(x, Wq, bq, Wk, bk, Wv, bv, ws, out);
}

// Round 4
// 51.448 us; speedup vs baseline: 1.2501x; 1.2501x over previous
//
#include <hip/hip_runtime.h>

#define CHUNK 8
#define NCHUNK 64
#define TDIM 512
#define HW 9216            // 96*96
#define NT 256
#define F4_PER_CH (HW/4)   // 2304 float4 per channel
#define ITERS (F4_PER_CH/NT) // 9

typedef float floatx4 __attribute__((ext_vector_type(4)));

__host__ __device__ constexpr int TRI(int c, int j) {       // c<=j incl diag, 36 entries
    return (c*(15-c))/2 + j;
}
__host__ __device__ constexpr int PairIdx(int c, int j) {   // c<j strict, 28 entries
    return 7*c - (c*(c-1))/2 + (j - c - 1);
}

__device__ __forceinline__ unsigned bf16_rne(float f) {
    unsigned u = __float_as_uint(f);
    return (u + 0x7fffu + ((u >> 16) & 1u)) >> 16;   // round-to-nearest-even
}
__device__ __forceinline__ float bf16_to_f(unsigned h16) {
    return __uint_as_float(h16 << 16);
}

// One block per chunk. Pass 1 reads x from HBM once, accumulates fp32
// Gram + row-sums, and stashes a bf16 copy of the slice in LDS (144 KiB).
// Pass 2 re-reads from LDS only -> fabric traffic drops from 321 MB to 170 MB.
__global__ __launch_bounds__(NT, 1)
void lcsap_kernel(const float* __restrict__ x,
                  const float* __restrict__ Wq, const float* __restrict__ bq,
                  const float* __restrict__ Wk, const float* __restrict__ bk,
                  const float* __restrict__ Wv, const float* __restrict__ bv,
                  float* __restrict__ out)
{
    const int bid = blockIdx.x;
    const int b   = bid >> 6;   // batch
    const int n   = bid & 63;   // chunk
    const int tid = threadIdx.x;
    const int lane = tid & 63;
    const int wid  = tid >> 6;

    const float* xb = x + ((size_t)(b*TDIM + n*CHUNK)) * HW;
    float* ob = out + ((size_t)(b*NCHUNK + n)) * HW;

    __shared__ uint2 xs[8][F4_PER_CH];   // 147456 B: bf16x4 per slot, planar [ch][f]
    __shared__ float red[4][44];
    __shared__ float Gf[64];   // full symmetric Gram
    __shared__ float sf[8];    // row sums
    __shared__ float Mld[64];  // M = attn * Wv
    __shared__ float tld[8];   // t = attn * bv

    // ---------------- pass 1: Gram + row sums, stash bf16 to LDS ----------------
    float g[36], sr[8];
    #pragma unroll
    for (int i = 0; i < 36; ++i) g[i] = 0.f;
    #pragma unroll
    for (int c = 0; c < 8; ++c) sr[c] = 0.f;

    floatx4 cur[8], nxt[8];
    #pragma unroll
    for (int c = 0; c < 8; ++c)
        cur[c] = reinterpret_cast<const floatx4*>(xb + (size_t)c*HW)[tid];

    #pragma unroll
    for (int it = 0; it < ITERS; ++it) {
        const int f = tid + it*NT;
        if (it + 1 < ITERS) {
            const int fn = f + NT;
            #pragma unroll
            for (int c = 0; c < 8; ++c)
                nxt[c] = reinterpret_cast<const floatx4*>(xb + (size_t)c*HW)[fn];
        }
        // stash bf16 copy (each thread later re-reads exactly these slots)
        #pragma unroll
        for (int c = 0; c < 8; ++c) {
            uint2 p;
            p.x = bf16_rne(cur[c][0]) | (bf16_rne(cur[c][1]) << 16);
            p.y = bf16_rne(cur[c][2]) | (bf16_rne(cur[c][3]) << 16);
            xs[c][f] = p;
        }
        // accumulate fp32 Gram + sums
        #pragma unroll
        for (int u = 0; u < 4; ++u) {
            float xv[8];
            #pragma unroll
            for (int c = 0; c < 8; ++c) xv[c] = cur[c][u];
            #pragma unroll
            for (int c = 0; c < 8; ++c) sr[c] += xv[c];
            #pragma unroll
            for (int c = 0; c < 8; ++c) {
                #pragma unroll
                for (int j = c; j < 8; ++j)
                    g[TRI(c,j)] += xv[c]*xv[j];
            }
        }
        #pragma unroll
        for (int c = 0; c < 8; ++c) cur[c] = nxt[c];
    }

    // wave butterfly reduce
    #pragma unroll
    for (int i = 0; i < 36; ++i) {
        g[i] += __shfl_xor(g[i], 1);  g[i] += __shfl_xor(g[i], 2);
        g[i] += __shfl_xor(g[i], 4);  g[i] += __shfl_xor(g[i], 8);
        g[i] += __shfl_xor(g[i], 16); g[i] += __shfl_xor(g[i], 32);
    }
    #pragma unroll
    for (int c = 0; c < 8; ++c) {
        sr[c] += __shfl_xor(sr[c], 1);  sr[c] += __shfl_xor(sr[c], 2);
        sr[c] += __shfl_xor(sr[c], 4);  sr[c] += __shfl_xor(sr[c], 8);
        sr[c] += __shfl_xor(sr[c], 16); sr[c] += __shfl_xor(sr[c], 32);
    }
    if (lane == 0) {
        #pragma unroll
        for (int i = 0; i < 36; ++i) red[wid][i] = g[i];
        #pragma unroll
        for (int c = 0; c < 8; ++c) red[wid][36+c] = sr[c];
    }
    __syncthreads();
    if (tid < 44) {
        float v = red[0][tid] + red[1][tid] + red[2][tid] + red[3][tid];
        if (tid < 36) {
            int c = 0, base = 0;
            for (; c < 8; ++c) { int w = 8 - c; if (tid < base + w) break; base += w; }
            int j = c + (tid - base);
            Gf[c*8+j] = v;
            Gf[j*8+c] = v;
        } else {
            sf[tid-36] = v;
        }
    }
    __syncthreads();

    // ---------------- tiny 8x8 attention on wave 0 ----------------
    if (tid < 64) {
        const int qi = tid >> 3;
        const int ki = tid & 7;
        float wq[8], wk[8];
        #pragma unroll
        for (int c = 0; c < 8; ++c) {
            wq[c] = Wq[n*64 + qi*8 + c];
            wk[c] = Wk[n*64 + ki*8 + c];
        }
        float sc = 0.f, qs = 0.f, ks_ = 0.f;
        #pragma unroll
        for (int c = 0; c < 8; ++c) {
            float tmp = 0.f;
            #pragma unroll
            for (int d = 0; d < 8; ++d) tmp += Gf[c*8+d]*wk[d];
            sc += wq[c]*tmp;
            qs += wq[c]*sf[c];
            ks_ += wk[c]*sf[c];
        }
        const float bqv = bq[n*8+qi];
        const float bkv = bk[n*8+ki];
        sc += qs*bkv + bqv*ks_ + (float)HW * bqv * bkv;
        sc *= (1.0f/96.0f);   // 1/sqrt(9216)

        float m = sc;
        m = fmaxf(m, __shfl_xor(m, 1, 8));
        m = fmaxf(m, __shfl_xor(m, 2, 8));
        m = fmaxf(m, __shfl_xor(m, 4, 8));
        float e = expf(sc - m);
        float se = e;
        se += __shfl_xor(se, 1, 8);
        se += __shfl_xor(se, 2, 8);
        se += __shfl_xor(se, 4, 8);
        const float attn = e / se;

        float mv = 0.f;
        #pragma unroll
        for (int k = 0; k < 8; ++k) {
            float ak = __shfl(attn, k, 8);
            mv += ak * Wv[n*64 + k*8 + ki];
        }
        Mld[qi*8 + ki] = mv;

        float tv = attn * bv[n*8 + ki];
        tv += __shfl_xor(tv, 1, 8);
        tv += __shfl_xor(tv, 2, 8);
        tv += __shfl_xor(tv, 4, 8);
        if (ki == 0) tld[qi] = tv;
    }
    __syncthreads();

    // ---------------- pass 2 (from LDS): pooled = x^T M x + t^T x ----------------
    float diag[8], tt[8], su[28];
    #pragma unroll
    for (int c = 0; c < 8; ++c) { diag[c] = Mld[c*9]; tt[c] = tld[c]; }
    #pragma unroll
    for (int c = 0; c < 8; ++c) {
        #pragma unroll
        for (int j = c+1; j < 8; ++j)
            su[PairIdx(c,j)] = Mld[c*8+j] + Mld[j*8+c];
    }

    #pragma unroll
    for (int it = 0; it < ITERS; ++it) {
        const int f = tid + it*NT;
        uint2 v[8];
        #pragma unroll
        for (int c = 0; c < 8; ++c) v[c] = xs[c][f];
        floatx4 o;
        #pragma unroll
        for (int u = 0; u < 4; ++u) {
            float xv[8];
            #pragma unroll
            for (int c = 0; c < 8; ++c) {
                unsigned w32 = (u < 2) ? v[c].x : v[c].y;
                unsigned h   = (u & 1) ? (w32 >> 16) : (w32 & 0xffffu);
                xv[c] = bf16_to_f(h);
            }
            float acc = 0.f;
            #pragma unroll
            for (int c = 0; c < 8; ++c) acc += tt[c]*xv[c];
            #pragma unroll
            for (int c = 0; c < 8; ++c) acc += diag[c]*xv[c]*xv[c];
            #pragma unroll
            for (int c = 0; c < 8; ++c) {
                #pragma unroll
                for (int j = c+1; j < 8; ++j)
                    acc += su[PairIdx(c,j)]*xv[c]*xv[j];
            }
            o[u] = acc;
        }
        reinterpret_cast<floatx4*>(ob)[f] = o;
    }
}

extern "C" void kernel_launch(void* const* d_in, const int* in_sizes, int n_in,
                              void* d_out, int out_size, void* d_ws, size_t ws_size,
                              hipStream_t stream) {
    const float* x  = (const float*)d_in[0];
    const float* Wq = (const float*)d_in[1];
    const float* bq = (const float*)d_in[2];
    const float* Wk = (const float*)d_in[3];
    const float* bk = (const float*)d_in[4];
    const float* Wv = (const float*)d_in[5];
    const float* bv = (const float*)d_in[6];
    float* out = (float*)d_out;

    lcsap_kernel<<<dim3(512), dim3(NT), 0, stream>>>(x, Wq, bq, Wk, bk, Wv, bv, out);
}